// Round 2
// baseline (3777.993 us; speedup 1.0000x reference)
//
#include <hip/hip_runtime.h>
#include <stdint.h>

#define N_TOK 4096
#define DS 2048
#define DB 5120
#define ISDM 13824
#define TOPK 128

typedef short bf16x8 __attribute__((ext_vector_type(8)));
typedef float f32x4 __attribute__((ext_vector_type(4)));

__device__ __forceinline__ ushort f2b(float f) {
  uint32_t u = __float_as_uint(f);
  u = (u + 0x7fff + ((u >> 16) & 1)) >> 16;
  return (ushort)u;
}
__device__ __forceinline__ float bl(uint32_t u) { return __uint_as_float(u << 16); }
__device__ __forceinline__ float bh(uint32_t u) { return __uint_as_float(u & 0xffff0000u); }

__device__ __forceinline__ float dot8(uint4 a, uint4 b) {
  return bl(a.x)*bl(b.x) + bh(a.x)*bh(b.x)
       + bl(a.y)*bl(b.y) + bh(a.y)*bh(b.y)
       + bl(a.z)*bl(b.z) + bh(a.z)*bh(b.z)
       + bl(a.w)*bl(b.w) + bh(a.w)*bh(b.w);
}
__device__ __forceinline__ void acc8(float* a, uint4 p, float g) {
  a[0] += g * bl(p.x); a[1] += g * bh(p.x);
  a[2] += g * bl(p.y); a[3] += g * bh(p.y);
  a[4] += g * bl(p.z); a[5] += g * bh(p.z);
  a[6] += g * bl(p.w); a[7] += g * bh(p.w);
}
__device__ __forceinline__ void store8(ushort* o, const float* a) {
  ushort4 u0; u0.x = f2b(a[0]); u0.y = f2b(a[1]); u0.z = f2b(a[2]); u0.w = f2b(a[3]);
  ushort4 u1; u1.x = f2b(a[4]); u1.y = f2b(a[5]); u1.z = f2b(a[6]); u1.w = f2b(a[7]);
  ((ushort4*)o)[0] = u0; ((ushort4*)o)[1] = u1;
}

// async global->LDS, 16B per lane. LDS dest = wave-uniform base + lane*16.
__device__ __forceinline__ void glds16(const ushort* g, ushort* l) {
  __builtin_amdgcn_global_load_lds(
      (const __attribute__((address_space(1))) void*)g,
      (__attribute__((address_space(3))) void*)l,
      16, 0, 0);
}

// ---------------- fp32 -> bf16 convert ----------------
__global__ void k_convert(const float* __restrict__ in, ushort* __restrict__ out, int n4) {
  int i = blockIdx.x * blockDim.x + threadIdx.x;
  if (i >= n4) return;
  float4 v = ((const float4*)in)[i];
  ushort4 o; o.x = f2b(v.x); o.y = f2b(v.y); o.z = f2b(v.z); o.w = f2b(v.w);
  ((ushort4*)out)[i] = o;
}

// ---------------- transpose sdm_down [DB][ISDM] f32 -> downT [ISDM][DB] bf16 ----------------
__global__ void k_transpose(const float* __restrict__ in, ushort* __restrict__ out) {
  __shared__ float tile[32][33];
  int ix = blockIdx.x * 32 + threadIdx.x;   // ISDM dim
  int iy0 = blockIdx.y * 32;                // DB dim
  #pragma unroll
  for (int j = 0; j < 4; j++)
    tile[threadIdx.y + j*8][threadIdx.x] = in[(size_t)(iy0 + threadIdx.y + j*8) * ISDM + ix];
  __syncthreads();
  int ox = iy0 + threadIdx.x;               // DB dim (contiguous out)
  int oy0 = blockIdx.x * 32;                // ISDM dim
  #pragma unroll
  for (int j = 0; j < 4; j++)
    out[(size_t)(oy0 + threadIdx.y + j*8) * DB + ox] = f2b(tile[threadIdx.x][threadIdx.y + j*8]);
}

// ---------------- LayerNorm -> bf16 ----------------
__global__ __launch_bounds__(256) void k_ln(const float* __restrict__ h,
                                            const float* __restrict__ sc,
                                            const float* __restrict__ bi,
                                            ushort* __restrict__ xo) {
  __shared__ float red[8];
  int row = blockIdx.x, tid = threadIdx.x;
  const float* hr = h + (size_t)row * DS;
  float v[8]; float s = 0.f;
  #pragma unroll
  for (int i = 0; i < 8; i++) { v[i] = hr[tid + i*256]; s += v[i]; }
  for (int o = 32; o; o >>= 1) s += __shfl_down(s, o);
  if ((tid & 63) == 0) red[tid >> 6] = s;
  __syncthreads();
  if (tid == 0) red[4] = red[0]+red[1]+red[2]+red[3];
  __syncthreads();
  float mu = red[4] * (1.0f/DS);
  float s2 = 0.f;
  #pragma unroll
  for (int i = 0; i < 8; i++) { float d = v[i]-mu; s2 += d*d; }
  for (int o = 32; o; o >>= 1) s2 += __shfl_down(s2, o);
  __syncthreads();
  if ((tid & 63) == 0) red[tid >> 6] = s2;
  __syncthreads();
  if (tid == 0) red[5] = red[0]+red[1]+red[2]+red[3];
  __syncthreads();
  float rs = rsqrtf(red[5]*(1.0f/DS) + 1e-5f);
  ushort* xr = xo + (size_t)row * DS;
  #pragma unroll
  for (int i = 0; i < 8; i++) {
    int c = tid + i*256;
    xr[c] = f2b((v[i]-mu)*rs*sc[c] + bi[c]);
  }
}

// ---------------- bf16 MFMA gemm_bt (m97 structure): C[m][n] = sum_k A[m][k]*B[n][k] ----------------
// EPI 0: store bf16   EPI 1: silu -> fp32   EPI 2: fp32 out = resid + v*tanh(gs[n])
template<int EPI>
__global__ __launch_bounds__(256) void k_gemm_bt(
    const ushort* __restrict__ A, const ushort* __restrict__ B,
    void* __restrict__ outp, int M, int N, int K,
    const float* __restrict__ resid, const float* __restrict__ gs)
{
  __shared__ __align__(16) ushort As[128*32];   // unpadded: global_load_lds needs contiguous lane order
  __shared__ __align__(16) ushort Bs[128*32];
  const int tid = threadIdx.x;

  // group-of-8 m-tile swizzle: consecutive blocks share B tiles for L2 reuse
  const int ntile = gridDim.x, mtile = gridDim.y;
  int bid = blockIdx.y * ntile + blockIdx.x;
  const int GRP = 8;
  int grp = bid / (GRP * ntile);
  int rem = bid % (GRP * ntile);
  int gm = mtile - grp * GRP; if (gm > GRP) gm = GRP;
  const int m0 = (grp * GRP + rem % gm) * 128;
  const int n0 = (rem / gm) * 128;

  const int wave = tid >> 6, lane = tid & 63;
  const int wm = (wave >> 1) * 64, wn = (wave & 1) * 64;
  const int quad = lane >> 4, l16 = lane & 15;

  // staging: wave w handles 1KB chunks {2w, 2w+1} of each tile; lane l -> 16B
  const int cA = wave * 2;
  const int r0 = cA * 16 + (lane >> 2);
  const int kc = (lane & 3) * 8;
  const ushort* ApG  = A + (size_t)(m0 + r0) * K + kc;
  const ushort* ApG2 = ApG + (size_t)16 * K;
  const ushort* BpG  = B + (size_t)(n0 + r0) * K + kc;
  const ushort* BpG2 = BpG + (size_t)16 * K;
  ushort* ldsA0 = &As[cA * 512];
  ushort* ldsA1 = ldsA0 + 512;
  ushort* ldsB0 = &Bs[cA * 512];
  ushort* ldsB1 = ldsB0 + 512;

  f32x4 acc[4][4];
  f32x4 zero = {0.f, 0.f, 0.f, 0.f};
  #pragma unroll
  for (int mt = 0; mt < 4; mt++)
    #pragma unroll
    for (int nt = 0; nt < 4; nt++) acc[mt][nt] = zero;

  for (int k0 = 0; k0 < K; k0 += 32) {
    __syncthreads();                       // prev iter's LDS reads done before overwrite
    glds16(ApG  + k0, ldsA0);
    glds16(ApG2 + k0, ldsA1);
    glds16(BpG  + k0, ldsB0);
    glds16(BpG2 + k0, ldsB1);
    __syncthreads();                       // implies vmcnt(0): staging complete
    bf16x8 af[4], bfr[4];
    #pragma unroll
    for (int mt = 0; mt < 4; mt++)
      af[mt] = *(const bf16x8*)&As[(wm + mt*16 + l16)*32 + quad*8];
    #pragma unroll
    for (int nt = 0; nt < 4; nt++)
      bfr[nt] = *(const bf16x8*)&Bs[(wn + nt*16 + l16)*32 + quad*8];
    #pragma unroll
    for (int mt = 0; mt < 4; mt++)
      #pragma unroll
      for (int nt = 0; nt < 4; nt++)
        acc[mt][nt] = __builtin_amdgcn_mfma_f32_16x16x32_bf16(af[mt], bfr[nt], acc[mt][nt], 0, 0, 0);
  }

  #pragma unroll
  for (int mt = 0; mt < 4; mt++) {
    #pragma unroll
    for (int nt = 0; nt < 4; nt++) {
      #pragma unroll
      for (int r = 0; r < 4; r++) {
        int row = m0 + wm + mt*16 + quad*4 + r;   // C/D: row=(lane>>4)*4+reg
        int col = n0 + wn + nt*16 + l16;          //      col=lane&15
        float v = acc[mt][nt][r];
        if (EPI == 0) {
          ((ushort*)outp)[(size_t)row * N + col] = f2b(v);
        } else if (EPI == 1) {
          ((float*)outp)[(size_t)row * N + col] = v / (1.0f + __expf(-v));
        } else {
          ((float*)outp)[(size_t)row * N + col] =
              resid[(size_t)row * N + col] + v * tanhf(gs[col]);
        }
      }
    }
  }
}

// ---------------- per-token top-K by |g|: 4-pass radix select on 31-bit keys ----------------
__global__ __launch_bounds__(256) void k_topk(const float* __restrict__ g,
                                              int* __restrict__ idx_out,
                                              float* __restrict__ gsel_out) {
  __shared__ uint32_t keys[ISDM];
  __shared__ int hist[256];
  __shared__ uint32_t sh_pref;
  __shared__ int sh_need;
  __shared__ int scnt, eqn;
  __shared__ int eqlist[256];
  int t = blockIdx.x, tid = threadIdx.x;
  const float* gr = g + (size_t)t * ISDM;
  for (int i = tid; i < ISDM; i += 256)
    keys[i] = __float_as_uint(gr[i]) & 0x7fffffffu;
  if (tid == 0) { sh_pref = 0; sh_need = TOPK; scnt = 0; eqn = 0; }
  __syncthreads();

  const int shifts[4] = {23, 15, 7, 0};
  const int nbits[4]  = {8, 8, 8, 7};
  #pragma unroll
  for (int p = 0; p < 4; p++) {
    const int sh = shifts[p], nb = nbits[p];
    const uint32_t msk = (1u << nb) - 1u;
    hist[tid] = 0;
    __syncthreads();
    uint32_t pref = sh_pref;
    const int hs = sh + nb;
    for (int i = tid; i < ISDM; i += 256) {
      uint32_t k = keys[i];
      if ((k >> hs) == pref) atomicAdd(&hist[(k >> sh) & msk], 1);
    }
    __syncthreads();
    if (tid == 0) {
      int need = sh_need;
      int b = (int)msk;
      while (need > hist[b]) { need -= hist[b]; b--; }
      sh_pref = (pref << nb) | (uint32_t)b;
      sh_need = need;
    }
    __syncthreads();
  }

  uint32_t thr = sh_pref;        // exact K-th largest key
  for (int i = tid; i < ISDM; i += 256) {
    uint32_t k = keys[i];
    if (k > thr) {
      int p = atomicAdd(&scnt, 1);
      idx_out[t*TOPK + p] = i;
      gsel_out[t*TOPK + p] = gr[i];
    } else if (k == thr) {
      int p = atomicAdd(&eqn, 1);
      if (p < 256) eqlist[p] = i;
    }
  }
  __syncthreads();
  if (tid == 0) {
    int need = sh_need;            // ties to include, lowest index first (jax tie-break)
    int ne = eqn < 256 ? eqn : 256;
    for (int a = 0; a < need; a++) {
      int best = a;
      for (int b = a+1; b < ne; b++) if (eqlist[b] < eqlist[best]) best = b;
      int tmp = eqlist[a]; eqlist[a] = eqlist[best]; eqlist[best] = tmp;
      int i = eqlist[a];
      idx_out[t*TOPK + scnt + a] = i;
      gsel_out[t*TOPK + scnt + a] = gr[i];
    }
  }
}

// ---------------- fused SDM: gu = gsel * <x, up[idx]>; rbig = sum_k gu_k * downT[idx_k] ----------------
__global__ __launch_bounds__(256) void k_sdm(const ushort* __restrict__ xbig,
                                             const ushort* __restrict__ up,
                                             const ushort* __restrict__ downT,
                                             const int* __restrict__ idx,
                                             const float* __restrict__ gsel,
                                             ushort* __restrict__ rbig) {
  __shared__ __align__(16) ushort xs[DB];   // 10 KB: token's x_big row
  __shared__ int sidx[TOPK];
  __shared__ float sgs[TOPK];
  __shared__ float sgu[TOPK];
  int t = blockIdx.x, tid = threadIdx.x;
  const int wave = tid >> 6, lane = tid & 63;

  const uint4* xg = (const uint4*)(xbig + (size_t)t * DB);
  #pragma unroll
  for (int j = 0; j < 3; j++) {
    int c = tid + j*256;
    if (c < DB/8) ((uint4*)xs)[c] = xg[c];
  }
  if (tid < TOPK) { sidx[tid] = idx[t*TOPK + tid]; sgs[tid] = gsel[t*TOPK + tid]; }
  __syncthreads();

  // phase 1: 128 gather-dots, 32 per wave
  const uint4* xl = (const uint4*)xs;
  for (int k = wave; k < TOPK; k += 4) {
    const uint4* ur = (const uint4*)(up + (size_t)sidx[k] * DB);
    float s = 0.f;
    #pragma unroll
    for (int j = 0; j < 10; j++)
      s += dot8(xl[lane + j*64], ur[lane + j*64]);
    for (int o = 32; o; o >>= 1) s += __shfl_down(s, o);
    if (lane == 0) sgu[k] = sgs[k] * s;
  }
  __syncthreads();

  // phase 2: accumulate 640 uint4 chunks of downT rows
  float a0[8] = {0,0,0,0,0,0,0,0};
  float a1[8] = {0,0,0,0,0,0,0,0};
  float a2[8] = {0,0,0,0,0,0,0,0};
  int c0 = tid, c1 = tid + 256, c2 = tid + 512;
  bool has2 = (c2 < 640);
  for (int k = 0; k < TOPK; k++) {
    const uint4* dr = (const uint4*)(downT + (size_t)sidx[k] * DB);
    float gk = sgu[k];
    acc8(a0, dr[c0], gk);
    acc8(a1, dr[c1], gk);
    if (has2) acc8(a2, dr[c2], gk);
  }
  ushort* outr = rbig + (size_t)t * DB;
  store8(outr + c0*8, a0);
  store8(outr + c1*8, a1);
  if (has2) store8(outr + c2*8, a2);
}

extern "C" void kernel_launch(void* const* d_in, const int* in_sizes, int n_in,
                              void* d_out, int out_size, void* d_ws, size_t ws_size,
                              hipStream_t stream) {
  const float* h        = (const float*)d_in[0];
  const float* ln_scale = (const float*)d_in[1];
  const float* ln_bias  = (const float*)d_in[2];
  const float* w_in     = (const float*)d_in[3];
  const float* w_out    = (const float*)d_in[4];
  const float* gate_sm  = (const float*)d_in[5];
  const float* sdm_gate = (const float*)d_in[6];
  const float* sdm_up   = (const float*)d_in[7];
  const float* sdm_down = (const float*)d_in[8];
  float* out = (float*)d_out;

  char* w = (char*)d_ws;
  size_t off = 0;
  auto alloc = [&](size_t bytes) -> void* {
    void* p = w + off; off += (bytes + 255) & ~(size_t)255; return p;
  };
  ushort* x_b    = (ushort*)alloc((size_t)N_TOK*DS*2);
  ushort* win_b  = (ushort*)alloc((size_t)DB*DS*2);
  ushort* wout_b = (ushort*)alloc((size_t)DS*DB*2);
  ushort* gate_b = (ushort*)alloc((size_t)ISDM*DB*2);
  ushort* up_b   = (ushort*)alloc((size_t)ISDM*DB*2);
  ushort* downT  = (ushort*)alloc((size_t)ISDM*DB*2);
  ushort* xbig_b = (ushort*)alloc((size_t)N_TOK*DB*2);
  float*  gfull  = (float*)alloc((size_t)N_TOK*ISDM*4);
  int*    idx    = (int*)alloc((size_t)N_TOK*TOPK*4);
  float*  gsel   = (float*)alloc((size_t)N_TOK*TOPK*4);
  ushort* rbig   = (ushort*)alloc((size_t)N_TOK*DB*2);

  // weight conversions (ws re-poisoned every call, so redo each launch)
  k_convert<<<(DB*DS/4 + 255)/256, 256, 0, stream>>>(w_in, win_b, DB*DS/4);
  k_convert<<<(DS*DB/4 + 255)/256, 256, 0, stream>>>(w_out, wout_b, DS*DB/4);
  k_convert<<<(ISDM*DB/4 + 255)/256, 256, 0, stream>>>(sdm_gate, gate_b, ISDM*DB/4);
  k_convert<<<(ISDM*DB/4 + 255)/256, 256, 0, stream>>>(sdm_up, up_b, ISDM*DB/4);
  k_transpose<<<dim3(ISDM/32, DB/32), dim3(32, 8), 0, stream>>>(sdm_down, downT);

  // LayerNorm
  k_ln<<<N_TOK, 256, 0, stream>>>(h, ln_scale, ln_bias, x_b);

  // proj_in: x_big = x @ w_in^T  [4096 x 5120], K=2048
  k_gemm_bt<0><<<dim3(DB/128, N_TOK/128), 256, 0, stream>>>(
      x_b, win_b, xbig_b, N_TOK, DB, DS, nullptr, nullptr);

  // gate: g_full = silu(x_big @ sdm_gate^T)  [4096 x 13824], K=5120
  k_gemm_bt<1><<<dim3(ISDM/128, N_TOK/128), 256, 0, stream>>>(
      xbig_b, gate_b, gfull, N_TOK, ISDM, DB, nullptr, nullptr);

  // top-k per token (radix select)
  k_topk<<<N_TOK, 256, 0, stream>>>(gfull, idx, gsel);

  // fused SDM gather-up + down
  k_sdm<<<N_TOK, 256, 0, stream>>>(xbig_b, up_b, downT, idx, gsel, rbig);

  // proj_out + tanh-gated residual -> out  [4096 x 2048], K=5120
  k_gemm_bt<2><<<dim3(DS/128, N_TOK/128), 256, 0, stream>>>(
      rbig, wout_b, out, N_TOK, DS, DB, h, gate_sm);
}